// Round 6
// baseline (3564.722 us; speedup 1.0000x reference)
//
#include <hip/hip_runtime.h>
#include <cstdint>

// ---------------------------------------------------------------------------
// SC-LSTM persistent kernel, MI355X (gfx950) — round 6.
//
//  vs round 5 (2.92 ms, 11.4 us/step; latency-bound: eff. 34 GB/s/CU vs 135
//  ceiling, occupancy 2 waves/SIMD):
//  * 1024 threads/block (16 waves = 4/SIMD) — 2x TLP. K split 2-way -> 4-way
//    (quarter q: x ks q*4..q*4+4, h ks 16+q*8..16+q*8+8); split-K partials
//    reduced via two-stage 8 KB LDS tree.
//  * Wd B-fragments prefetched into registers before the d-wait poll.
//  * x-part GEMM of step t+1 still prefetched between barrier arrival and
//    epoch poll.
//  Everything else as round 5: split-precision fp16 MFMA (hi+lo), RELAXED-
//  only agent atomics (no wbl2 on hot path), LDS-resident gate/r weights,
//  MFMA-fragment-layout trajectories (write-once slots), hierarchical
//  grouped barrier with broadcast epoch mirrors.
// ---------------------------------------------------------------------------

#define TT   256
#define BB   64
#define IC   512
#define HC   1024
#define DC   100
#define NG   4096
#define NRB  7
#define NBLK 256
#define NTHR 1024

typedef _Float16 f16;
typedef f16   f16x8 __attribute__((ext_vector_type(8)));
typedef float f32x4 __attribute__((ext_vector_type(4)));
typedef unsigned long long u64;

// ---- workspace layout (bytes) ----
#define WS_BAR   0ull                          // 8192 B of counters/mirrors
#define WS_X     8192ull                       // x A-frags: 1048576 * 32 B
#define WS_WDF   (WS_X + 33554432ull)          // Wd B-frags: 16384 * 32 B
#define WS_D     (WS_WDF + 524288ull)          // d A-frag slots
#define D_SLOT   32768ull
#define H_SLOT   262144ull
#define WS_NEED_TRAJ (WS_D + 257ull * D_SLOT + 257ull * H_SLOT)

// barrier word indices (spaced 64 uints = 256 B, all separate lines)
#define BAR_GRP(g)   (64 * (g))          // 8 group arrival counters
#define BAR_ROOT     512                 // root arrival counter
#define BAR_EPOCH(g) (576 + 64 * (g))    // 8 epoch mirrors
#define BAR_DCNT     1088                // d-producer counter
#define BAR_DEP(g)   (1152 + 64 * (g))   // 8 depoch mirrors

#define OFF_H  ((size_t)TT * BB * HC)
#define OFF_C  (OFF_H + (size_t)BB * HC)
#define OFF_D  (OFF_H + 2ull * BB * HC)

// ------------------------------------------------------------- helpers

__device__ __forceinline__ void split(float v, f16& hi, f16& lo) {
    hi = (f16)v;
    lo = (f16)(v - (float)hi);
}

__device__ __forceinline__ float fast_sigmoid(float x) {
    return 1.0f / (1.0f + __expf(-x));
}
__device__ __forceinline__ float fast_tanh(float x) {
    float ax = fabsf(x);
    float e  = __expf(-2.0f * ax);
    float r  = (1.0f - e) / (1.0f + e);
    return copysignf(r, x);
}

__device__ __forceinline__ void astore8(char* p, u64 v) {
    __hip_atomic_store((u64*)p, v, __ATOMIC_RELAXED, __HIP_MEMORY_SCOPE_AGENT);
}
__device__ __forceinline__ void astore4(unsigned* p, unsigned v) {
    __hip_atomic_store(p, v, __ATOMIC_RELAXED, __HIP_MEMORY_SCOPE_AGENT);
}
__device__ __forceinline__ unsigned aload4(const unsigned* p) {
    return __hip_atomic_load(p, __ATOMIC_RELAXED, __HIP_MEMORY_SCOPE_AGENT);
}
__device__ __forceinline__ unsigned aadd4(unsigned* p) {
    return __hip_atomic_fetch_add(p, 1u, __ATOMIC_RELAXED, __HIP_MEMORY_SCOPE_AGENT);
}

// 32B A-frag load (hi 16B + lo 16B). TRAJ: normal cached. else: L2-bypass.
template <bool TRAJ>
__device__ __forceinline__ void loadAB(const char* p, f16x8& hi, f16x8& lo) {
    if constexpr (TRAJ) {
        hi = *(const f16x8*)p;
        lo = *(const f16x8*)(p + 16);
    } else {
        union { u64 q[2]; f16x8 v; } a, b;
        const u64* q = (const u64*)p;
        a.q[0] = __hip_atomic_load(q + 0, __ATOMIC_RELAXED, __HIP_MEMORY_SCOPE_AGENT);
        a.q[1] = __hip_atomic_load(q + 1, __ATOMIC_RELAXED, __HIP_MEMORY_SCOPE_AGENT);
        b.q[0] = __hip_atomic_load(q + 2, __ATOMIC_RELAXED, __HIP_MEMORY_SCOPE_AGENT);
        b.q[1] = __hip_atomic_load(q + 3, __ATOMIC_RELAXED, __HIP_MEMORY_SCOPE_AGENT);
        hi = a.v; lo = b.v;
    }
}

// ------------------------------------------------------------- prep kernels

__global__ void prep_x(const float* __restrict__ x, char* __restrict__ xF) {
    const int i = blockIdx.x * blockDim.x + threadIdx.x;   // < 1048576
    const int lane = i & 63, ks = (i >> 6) & 15, rg = (i >> 10) & 3, t = i >> 12;
    const int m = lane & 15, quad = lane >> 4;
    const float* src = x + (size_t)(t * BB + rg * 16 + m) * IC + ks * 32 + quad * 8;
    f16 hi[8], lo[8];
#pragma unroll
    for (int j = 0; j < 8; ++j) split(src[j], hi[j], lo[j]);
    char* dst = xF + (size_t)i * 32;
    *(f16x8*)dst        = *(f16x8*)hi;
    *(f16x8*)(dst + 16) = *(f16x8*)lo;
}

__global__ void prep_wdf(const float* __restrict__ Wd, char* __restrict__ WDF) {
    const int i = blockIdx.x * blockDim.x + threadIdx.x;   // < 16384
    const int lane = i & 63, kd = (i >> 6) & 3, s = i >> 8;
    const int n = lane & 15, quad = lane >> 4;
    f16 hi[8], lo[8];
#pragma unroll
    for (int j = 0; j < 8; ++j) {
        const int k = kd * 32 + quad * 8 + j;
        const float v = (k < DC) ? Wd[(size_t)k * HC + 16 * s + n] : 0.0f;
        split(v, hi[j], lo[j]);
    }
    char* dst = WDF + (size_t)i * 32;
    *(f16x8*)dst        = *(f16x8*)hi;
    *(f16x8*)(dst + 16) = *(f16x8*)lo;
}

__global__ void prep_h0(const float* __restrict__ h0, char* __restrict__ hT,
                        unsigned* __restrict__ bar) {
    const int i = blockIdx.x * blockDim.x + threadIdx.x;   // < 8192
    const int lane = i & 63, ks = (i >> 6) & 31, rg = i >> 11;
    const int m = lane & 15, quad = lane >> 4;
    const float* src = h0 + (size_t)(rg * 16 + m) * HC + ks * 32 + quad * 8;
    f16 hi[8], lo[8];
#pragma unroll
    for (int j = 0; j < 8; ++j) split(src[j], hi[j], lo[j]);
    char* dst = hT + (size_t)i * 32;
    *(f16x8*)dst        = *(f16x8*)hi;
    *(f16x8*)(dst + 16) = *(f16x8*)lo;
    if (i < 2048) bar[i] = 0u;
}

__global__ void prep_d0(const float* __restrict__ d0, char* __restrict__ dT) {
    const int i = blockIdx.x * blockDim.x + threadIdx.x;   // < 1024
    const int lane = i & 63, kd = (i >> 6) & 3, rg = i >> 8;
    const int m = lane & 15, quad = lane >> 4;
    f16 hi[8], lo[8];
#pragma unroll
    for (int j = 0; j < 8; ++j) {
        const int k = kd * 32 + quad * 8 + j;
        const float v = (k < DC) ? d0[(size_t)(rg * 16 + m) * DC + k] : 0.0f;
        split(v, hi[j], lo[j]);
    }
    char* dst = dT + (size_t)i * 32;
    *(f16x8*)dst        = *(f16x8*)hi;
    *(f16x8*)(dst + 16) = *(f16x8*)lo;
}

// ------------------------------------------------------------- GEMM pieces

#define MFMA16(a, b, c) __builtin_amdgcn_mfma_f32_16x16x32_f16((a), (b), (c), 0, 0, 0)

// x-part: ks in [q*4, q*4+4), normal cached loads, accs zero-inited.
__device__ __forceinline__ void xpart_gemm(
    const char* __restrict__ xb, const f16* __restrict__ BFH,
    const f16* __restrict__ BFL, const f16* __restrict__ RBF,
    int q, int lane, bool withr,
    f32x4& ghh, f32x4& ghl, f32x4& glh, f32x4& rh, f32x4& rl) {
    ghh = f32x4{0,0,0,0}; ghl = f32x4{0,0,0,0}; glh = f32x4{0,0,0,0};
    rh  = f32x4{0,0,0,0}; rl  = f32x4{0,0,0,0};
    const int k0 = q * 4;
#pragma unroll
    for (int i = 0; i < 4; ++i) {
        const int ks = k0 + i;
        const char* ap = xb + (size_t)(ks * 64 + lane) * 32;
        f16x8 ah = *(const f16x8*)ap;
        f16x8 al = *(const f16x8*)(ap + 16);
        f16x8 bh = *(const f16x8*)(BFH + (ks * 64 + lane) * 8);
        f16x8 bl = *(const f16x8*)(BFL + (ks * 64 + lane) * 8);
        ghh = MFMA16(ah, bh, ghh);
        ghl = MFMA16(ah, bl, ghl);
        glh = MFMA16(al, bh, glh);
        if (withr) {
            f16x8 rb = *(const f16x8*)(RBF + (ks * 64 + lane) * 8);
            rh = MFMA16(ah, rb, rh);
            rl = MFMA16(al, rb, rl);
        }
    }
}

// h-part: ks in [16+q*8, 16+q*8+8), trajectory loads.
template <bool TRAJ>
__device__ __forceinline__ void hpart_gemm(
    const char* __restrict__ hb, const f16* __restrict__ BFH,
    const f16* __restrict__ BFL, const f16* __restrict__ RBF,
    int q, int lane, bool withr,
    f32x4& ghh, f32x4& ghl, f32x4& glh, f32x4& rh, f32x4& rl) {
    const int k0 = 16 + q * 8;
#pragma unroll
    for (int i = 0; i < 8; ++i) {
        const int ks = k0 + i;
        f16x8 ah, al;
        loadAB<TRAJ>(hb + (size_t)((ks - 16) * 64 + lane) * 32, ah, al);
        f16x8 bh = *(const f16x8*)(BFH + (ks * 64 + lane) * 8);
        f16x8 bl = *(const f16x8*)(BFL + (ks * 64 + lane) * 8);
        ghh = MFMA16(ah, bh, ghh);
        ghl = MFMA16(ah, bl, ghl);
        glh = MFMA16(al, bh, glh);
        if (withr) {
            f16x8 rb = *(const f16x8*)(RBF + (ks * 64 + lane) * 8);
            rh = MFMA16(ah, rb, rh);
            rl = MFMA16(al, rb, rl);
        }
    }
}

// ------------------------------------------------------------- main kernel

template <bool TRAJ>
__global__ __launch_bounds__(NTHR) void sclstm_main(
    const char* __restrict__ xF, const char* __restrict__ WDF,
    char* hT, char* dT,
    const float* __restrict__ Wx, const float* __restrict__ Wh,
    const float* __restrict__ Wrx, const float* __restrict__ Wrh,
    const float* __restrict__ bvec, const float* __restrict__ c0,
    const float* __restrict__ d0, float* __restrict__ out,
    unsigned* bar) {

    const int g    = blockIdx.x;
    const int grp  = g & 7;
    const int tid  = threadIdx.x;
    const int w    = tid >> 6;              // 0..15
    const int q    = w >> 2;                // K quarter
    const int wrow = w & 3;                 // 16-row A tile
    const int lane = tid & 63;
    const int n    = lane & 15;
    const int quad = lane >> 4;
    const bool withr = (g < NRB);

    // LDS map (160,000 B total)
    __shared__ __align__(16) char smem[160000];
    f16*  BFH = (f16*)(smem);                               // [48][64][8] gate B hi
    f16*  BFL = (f16*)(smem + 49152);                       // [48][64][8] gate B lo
    f16*  RBF = (f16*)(smem + 98304);                       // [48][64][8] r B hi
    float (*GL)[17]    = (float(*)[17])(smem + 147456);     // [64][17] gate preacts
    float (*TST)[16]   = (float(*)[16])(smem + 147456);     // stage (overlay GL)
    f32x4 (*PARTs)[4][64] = (f32x4(*)[4][64])(smem + 151808); // [2][4][64] split-K
    f16 (*DST)[32][16] = (f16(*)[32][16])(smem + 151808);   // [4][32][16] d stage (overlay)
    float (*DAL)[5]    = (float(*)[5])(smem + 151808);      // [64][5] (overlay)
    f16 (*HST)[16][8]  = (f16(*)[16][8])(smem + 151808 + 1280); // [4][16][8] h stage

    // ---------------- one-time: gate B-frags in LDS (4 ks rows per iter)
    for (int ks4 = 0; ks4 < 12; ++ks4) {
        if (tid < 512) {
            const int krow = tid >> 2, qq = tid & 3;        // krow 0..127
            const int k = ks4 * 128 + krow;
            const float* W = (k < IC) ? (Wx + (size_t)k * NG)
                                      : (Wh + (size_t)(k - IC) * NG);
            const float4 v = *(const float4*)(W + qq * HC + 4 * g);
            // stage 128 k-rows: two TST passes of 64 via direct f16 conversion
            // (write straight to BFH/BFL using the known frag mapping)
            // frag coords: ks = k>>5, le = (quad'=((k>>3)&3))*16 + n', j = k&7
            const int ks = k >> 5, j = k & 7, qd = (k >> 3) & 3;
#pragma unroll
            for (int e = 0; e < 4; ++e) {
                const float s = (&v.x)[e];
                const int col = qq * 4 + e;                 // 0..15
                f16 hi, lo; split(s, hi, lo);
                const int le = qd * 16 + col;
                BFH[(ks * 64 + le) * 8 + j] = hi;
                BFL[(ks * 64 + le) * 8 + j] = lo;
            }
        }
        __syncthreads();
    }
    // one-time: r B-frags (hi only, alpha folded)
    if (withr) {
        for (int ks4 = 0; ks4 < 12; ++ks4) {
            if (tid < 512) {
                const int krow = tid >> 2, cg = tid & 3;
                const int k = ks4 * 128 + krow;
                const int col0 = 16 * g + cg * 4;
                float4 v = make_float4(0.f, 0.f, 0.f, 0.f);
                if (col0 < DC) {
                    if (k < IC) v = *(const float4*)(Wrx + (size_t)k * DC + col0);
                    else {
                        float4 u = *(const float4*)(Wrh + (size_t)(k - IC) * DC + col0);
                        v = make_float4(0.5f * u.x, 0.5f * u.y, 0.5f * u.z, 0.5f * u.w);
                    }
                }
                const int ks = k >> 5, j = k & 7, qd = (k >> 3) & 3;
#pragma unroll
                for (int e = 0; e < 4; ++e) {
                    const int le = qd * 16 + cg * 4 + e;
                    RBF[(ks * 64 + le) * 8 + j] = (f16)(&v.x)[e];
                }
            }
            __syncthreads();
        }
    }

    // ---------------- per-thread state
    const float biasv = bvec[(n >> 2) * HC + g * 4 + (n & 3)];
    const int row2 = tid >> 2, jj = tid & 3;        // valid for tid < 256
    float c = 0.f;
    if (tid < 256) c = c0[(size_t)row2 * HC + 4 * g + jj];
    float d_prev[4] = {0.f, 0.f, 0.f, 0.f};
    if (withr && q == 0 && 16 * g + n < DC) {
#pragma unroll
        for (int r = 0; r < 4; ++r)
            d_prev[r] = d0[(size_t)(wrow * 16 + quad * 4 + r) * DC + 16 * g + n];
    }
    __syncthreads();

    const int ksh = g >> 3, qkh = (g & 7) >> 1, jw = (g & 1) * 4;   // h-frag coords

    // prime accumulators with x-part of step 0
    f32x4 ghh, ghl, glh, rh, rl;
    xpart_gemm(xF + (size_t)wrow * 32768, BFH, BFL, RBF, q, lane, withr,
               ghh, ghl, glh, rh, rl);

    // ---------------- time loop
    for (int t = 0; t < TT; ++t) {
        const int slH  = TRAJ ? t : (t & 1);
        const int slH1 = TRAJ ? (t + 1) : ((t + 1) & 1);
        const int slD1 = slH1;

        // ---- phase 1: h-part GEMM (x-part already accumulated) ----
        hpart_gemm<TRAJ>(hT + (size_t)slH * H_SLOT + (size_t)wrow * 65536,
                         BFH, BFL, RBF, q, lane, withr, ghh, ghl, glh, rh, rl);
        f32x4 accg = ghh + ghl + glh;
        f32x4 accr = rh + rl;

        // ---- two-stage 4-way split-K reduction (gate) ----
        if (q >= 2) PARTs[q - 2][wrow][lane] = accg;
        __syncthreads();
        if (q < 2) accg += PARTs[q][wrow][lane];
        __syncthreads();
        if (q == 1) PARTs[0][wrow][lane] = accg;
        __syncthreads();
        if (q == 0) accg += PARTs[0][wrow][lane];
        // ---- same for r (r-blocks only) ----
        if (withr) {
            __syncthreads();
            if (q >= 2) PARTs[q - 2][wrow][lane] = accr;
            __syncthreads();
            if (q < 2) accr += PARTs[q][wrow][lane];
            __syncthreads();
            if (q == 1) PARTs[0][wrow][lane] = accr;
            __syncthreads();
            if (q == 0) accr += PARTs[0][wrow][lane];
        }

        // ---- phase 2: gate preacts -> LDS ----
        if (q == 0) {
#pragma unroll
            for (int r = 0; r < 4; ++r)
                GL[wrow * 16 + quad * 4 + r][n] = accg[r] + biasv;
        }

        // ---- phase 3 (blocks 0..6): d update + publish ----
        if (withr) {
            if (q == 0) {
#pragma unroll
                for (int r = 0; r < 4; ++r) {
                    const float rv = fast_sigmoid(accr[r]);
                    const float dn = rv * d_prev[r];
                    d_prev[r] = dn;
                    f16 hi, lo; split(dn, hi, lo);
                    const int sr = (n >> 3) * 16 + quad * 4 + r;
                    DST[wrow][sr][n & 7]       = hi;
                    DST[wrow][sr][8 + (n & 7)] = lo;
                }
                if (t == TT - 1 && 16 * g + n < DC) {
#pragma unroll
                    for (int r = 0; r < 4; ++r)
                        out[OFF_D + (size_t)(wrow * 16 + quad * 4 + r) * DC + 16 * g + n] = d_prev[r];
                }
            }
            __syncthreads();
            if (tid < 256) {
                const int rg = tid >> 6, l32 = (tid >> 1) & 31, part = tid & 1;
                char* base = dT + (size_t)slD1 * D_SLOT;
                char* dp = base + (size_t)((rg * 4 + (g >> 1)) * 64 + 32 * (g & 1) + l32) * 32
                           + part * 8;
                astore8(dp,      *(const u64*)&DST[rg][l32][part * 4]);
                astore8(dp + 16, *(const u64*)&DST[rg][l32][8 + part * 4]);
                if (g == 6) {   // zero-fill d-frag cols 112..127
                    char* zp = base + (size_t)((rg * 4 + 3) * 64 + 32 + l32) * 32 + part * 8;
                    astore8(zp, 0ull); astore8(zp + 16, 0ull);
                }
            }
            __syncthreads();   // drain d stores (vmcnt 0) before relaxed signal
            if (tid == 0) {
                unsigned o = aadd4(bar + BAR_DCNT);
                if (o % NRB == NRB - 1) {   // last d producer this step
#pragma unroll
                    for (int e = 0; e < 8; ++e) astore4(bar + BAR_DEP(e), t + 1);
                }
            }
        } else {
            __syncthreads();   // make GL visible for activation precompute
        }

        // ---- precompute gate activations (off the post-d-wait path) ----
        float iv = 0.f, fv = 0.f, gv = 0.f, ov = 0.f;
        if (tid < 256) {
            iv = fast_sigmoid(GL[row2][jj]);
            fv = fast_sigmoid(GL[row2][4 + jj]);
            gv = fast_tanh(GL[row2][8 + jj]);
            ov = fast_sigmoid(GL[row2][12 + jj]);
        }

        // ---- prefetch Wd B-frags into registers (L2-hot, step-invariant) ----
        f16x8 wph[4], wpl[4];
        if (q == 0) {
            const char* wb = WDF + (size_t)(g >> 2) * 8192;
#pragma unroll
            for (int kd = 0; kd < 4; ++kd) {
                const char* wp = wb + (size_t)(kd * 64 + lane) * 32;
                wph[kd] = *(const f16x8*)wp;
                wpl[kd] = *(const f16x8*)(wp + 16);
            }
        }

        // ---- phase 4: wait for d-ready broadcast ----
        if (tid == 0) {
            while (aload4(bar + BAR_DEP(grp)) < (unsigned)(t + 1))
                __builtin_amdgcn_s_sleep(1);
        }
        __syncthreads();

        // ---- phase 5: da = d_new @ Wd (K=128, split precision) ----
        if (q == 0) {
            f32x4 da = {0,0,0,0};
            const char* db = dT + (size_t)slD1 * D_SLOT + (size_t)wrow * 8192;
#pragma unroll
            for (int kd = 0; kd < 4; ++kd) {
                f16x8 dh, dl;
                loadAB<TRAJ>(db + (size_t)(kd * 64 + lane) * 32, dh, dl);
                da = MFMA16(dh, wph[kd], da);
                da = MFMA16(dh, wpl[kd], da);
                da = MFMA16(dl, wph[kd], da);
            }
            const int wo = n - 4 * (g & 3);
            if ((unsigned)wo < 4u) {
#pragma unroll
                for (int r = 0; r < 4; ++r)
                    DAL[wrow * 16 + quad * 4 + r][wo] = da[r];
            }
        }
        __syncthreads();

        // ---- phase 6: c/h update (1 state/thread, threads 0..255) ----
        if (tid < 256) {
            c = fv * c + iv * gv + fast_tanh(DAL[row2][jj]);
            const float h = ov * fast_tanh(c);
            out[((size_t)t * BB + row2) * HC + 4 * g + jj] = h;
            f16 hh_, hl_; split(h, hh_, hl_);
            HST[row2 >> 4][row2 & 15][jj]     = hh_;
            HST[row2 >> 4][row2 & 15][4 + jj] = hl_;
            if (t == TT - 1) {
                out[OFF_H + (size_t)row2 * HC + 4 * g + jj] = h;
                out[OFF_C + (size_t)row2 * HC + 4 * g + jj] = c;
            }
        }
        __syncthreads();

        // ---- phase 7: publish h fragment (coalesced 8B stores) ----
        if (tid < 128) {
            const int rg = tid >> 5, m = (tid >> 1) & 15, hlf = tid & 1;
            const u64 v = *(const u64*)&HST[rg][m][hlf * 4];
            char* p = hT + (size_t)slH1 * H_SLOT
                      + (size_t)((rg * 32 + ksh) * 64 + qkh * 16 + m) * 32
                      + hlf * 16 + jw * 2;
            astore8(p, v);
        }
        __syncthreads();   // drain h stores (vmcnt 0) before relaxed arrival

        // ---- phase 8: split-phase hierarchical barrier ----
        if (tid == 0) {
            unsigned o = aadd4(bar + BAR_GRP(grp));
            if ((o & 31) == 31) {           // last in group
                unsigned o2 = aadd4(bar + BAR_ROOT);
                if ((o2 & 7) == 7) {        // last overall: broadcast epoch
#pragma unroll
                    for (int e = 0; e < 8; ++e) astore4(bar + BAR_EPOCH(e), t + 1);
                }
            }
        }

        // ---- overlap: x-part GEMM of step t+1 while epoch propagates ----
        if (t + 1 < TT) {
            xpart_gemm(xF + (size_t)((t + 1) * 4 + wrow) * 32768,
                       BFH, BFL, RBF, q, lane, withr, ghh, ghl, glh, rh, rl);
        }

        if (tid == 0) {
            while (aload4(bar + BAR_EPOCH(grp)) < (unsigned)(t + 1))
                __builtin_amdgcn_s_sleep(1);
        }
        __syncthreads();
    }
}

// ------------------------------------------------------------- launch

extern "C" void kernel_launch(void* const* d_in, const int* in_sizes, int n_in,
                              void* d_out, int out_size, void* d_ws, size_t ws_size,
                              hipStream_t stream) {
    const float* x   = (const float*)d_in[0];
    const float* h0  = (const float*)d_in[1];
    const float* c0  = (const float*)d_in[2];
    const float* d0  = (const float*)d_in[3];
    const float* Wx  = (const float*)d_in[4];
    const float* Wh  = (const float*)d_in[5];
    const float* bv  = (const float*)d_in[6];
    const float* Wrx = (const float*)d_in[7];
    const float* Wrh = (const float*)d_in[8];
    const float* Wd  = (const float*)d_in[9];
    float* out = (float*)d_out;

    char* ws = (char*)d_ws;
    const bool traj = (ws_size >= (size_t)WS_NEED_TRAJ);
    const int dslots = traj ? 257 : 2;

    unsigned* bar = (unsigned*)(ws + WS_BAR);
    char* xF  = ws + WS_X;
    char* WDF = ws + WS_WDF;
    char* dT  = ws + WS_D;
    char* hT  = dT + (size_t)dslots * D_SLOT;

    prep_x<<<4096, 256, 0, stream>>>(x, xF);
    prep_wdf<<<64, 256, 0, stream>>>(Wd, WDF);
    prep_h0<<<32, 256, 0, stream>>>(h0, hT, bar);
    prep_d0<<<4, 256, 0, stream>>>(d0, dT);

    if (traj)
        sclstm_main<true><<<NBLK, NTHR, 0, stream>>>(xF, WDF, hT, dT, Wx, Wh, Wrx, Wrh,
                                                     bv, c0, d0, out, bar);
    else
        sclstm_main<false><<<NBLK, NTHR, 0, stream>>>(xF, WDF, hT, dT, Wx, Wh, Wrx, Wrh,
                                                      bv, c0, d0, out, bar);
}

// Round 7
// 2449.966 us; speedup vs baseline: 1.4550x; 1.4550x over previous
//
#include <hip/hip_runtime.h>
#include <cstdint>

// ---------------------------------------------------------------------------
// SC-LSTM persistent kernel, MI355X (gfx950) — round 7.
//
//  vs round 5 (2.92 ms best; round 6's 16-wave config regressed -> reverted):
//  * h recurrent state fp16 HI-ONLY: h-loop loads 16 B/lane/ks (was 32) and
//    2 MFMA streams (was 3). Weight-side split precision (systematic error)
//    retained; h-side quantization is a ~1e-3 random walk (margin 9.5x).
//  * r-first: r-blocks run a separate r-only h-loop FIRST (ah frags cached
//    in 64 VGPRs), publish d ~1us into the step -> d-wait of the 249 gate
//    blocks is hidden behind their own gate GEMM. Cached frags then feed the
//    gate h-loop with zero reloads.
//  * Wd B-fragments hoisted out of the time loop (step-invariant).
//  Everything else as round 5: RELAXED-only agent atomics, LDS-resident
//  weights, fragment-layout trajectories (write-once slots), hierarchical
//  grouped barrier + split-phase x-prefetch.
// ---------------------------------------------------------------------------

#define TT   256
#define BB   64
#define IC   512
#define HC   1024
#define DC   100
#define NG   4096
#define NRB  7
#define NBLK 256
#define NTHR 512

typedef _Float16 f16;
typedef f16   f16x8 __attribute__((ext_vector_type(8)));
typedef float f32x4 __attribute__((ext_vector_type(4)));
typedef unsigned long long u64;

// ---- workspace layout (bytes) ----
#define WS_BAR   0ull                          // 8192 B of counters/mirrors
#define WS_X     8192ull                       // x A-frags: 1048576 * 32 B
#define WS_WDF   (WS_X + 33554432ull)          // Wd B-frags: 16384 * 32 B
#define WS_D     (WS_WDF + 524288ull)          // d A-frag slots
#define D_SLOT   32768ull
#define H_SLOT   131072ull                     // h hi-only: 4 rg * 32 ks * 64 * 16 B
#define WS_NEED_TRAJ (WS_D + 257ull * D_SLOT + 257ull * H_SLOT)

// barrier word indices (spaced 64 uints = 256 B, all separate lines)
#define BAR_GRP(g)   (64 * (g))          // 8 group arrival counters
#define BAR_ROOT     512                 // root arrival counter
#define BAR_EPOCH(g) (576 + 64 * (g))    // 8 epoch mirrors
#define BAR_DCNT     1088                // d-producer counter
#define BAR_DEP(g)   (1152 + 64 * (g))   // 8 depoch mirrors

#define OFF_H  ((size_t)TT * BB * HC)
#define OFF_C  (OFF_H + (size_t)BB * HC)
#define OFF_D  (OFF_H + 2ull * BB * HC)

// ------------------------------------------------------------- helpers

__device__ __forceinline__ void split(float v, f16& hi, f16& lo) {
    hi = (f16)v;
    lo = (f16)(v - (float)hi);
}

__device__ __forceinline__ float fast_sigmoid(float x) {
    return 1.0f / (1.0f + __expf(-x));
}
__device__ __forceinline__ float fast_tanh(float x) {
    float ax = fabsf(x);
    float e  = __expf(-2.0f * ax);
    float r  = (1.0f - e) / (1.0f + e);
    return copysignf(r, x);
}

__device__ __forceinline__ void astore8(char* p, u64 v) {
    __hip_atomic_store((u64*)p, v, __ATOMIC_RELAXED, __HIP_MEMORY_SCOPE_AGENT);
}
__device__ __forceinline__ void astore4(unsigned* p, unsigned v) {
    __hip_atomic_store(p, v, __ATOMIC_RELAXED, __HIP_MEMORY_SCOPE_AGENT);
}
__device__ __forceinline__ unsigned aload4(const unsigned* p) {
    return __hip_atomic_load(p, __ATOMIC_RELAXED, __HIP_MEMORY_SCOPE_AGENT);
}
__device__ __forceinline__ unsigned aadd4(unsigned* p) {
    return __hip_atomic_fetch_add(p, 1u, __ATOMIC_RELAXED, __HIP_MEMORY_SCOPE_AGENT);
}

// 16B hi-only A-frag load. TRAJ: normal cached. else: L2-bypass atomics.
template <bool TRAJ>
__device__ __forceinline__ f16x8 loadA16(const char* p) {
    if constexpr (TRAJ) {
        return *(const f16x8*)p;
    } else {
        union { u64 q[2]; f16x8 v; } a;
        const u64* q = (const u64*)p;
        a.q[0] = __hip_atomic_load(q + 0, __ATOMIC_RELAXED, __HIP_MEMORY_SCOPE_AGENT);
        a.q[1] = __hip_atomic_load(q + 1, __ATOMIC_RELAXED, __HIP_MEMORY_SCOPE_AGENT);
        return a.v;
    }
}

// 32B hi+lo A-frag load (x, d).
template <bool TRAJ>
__device__ __forceinline__ void loadAB(const char* p, f16x8& hi, f16x8& lo) {
    if constexpr (TRAJ) {
        hi = *(const f16x8*)p;
        lo = *(const f16x8*)(p + 16);
    } else {
        union { u64 q[2]; f16x8 v; } a, b;
        const u64* q = (const u64*)p;
        a.q[0] = __hip_atomic_load(q + 0, __ATOMIC_RELAXED, __HIP_MEMORY_SCOPE_AGENT);
        a.q[1] = __hip_atomic_load(q + 1, __ATOMIC_RELAXED, __HIP_MEMORY_SCOPE_AGENT);
        b.q[0] = __hip_atomic_load(q + 2, __ATOMIC_RELAXED, __HIP_MEMORY_SCOPE_AGENT);
        b.q[1] = __hip_atomic_load(q + 3, __ATOMIC_RELAXED, __HIP_MEMORY_SCOPE_AGENT);
        hi = a.v; lo = b.v;
    }
}

// ------------------------------------------------------------- prep kernels

__global__ void prep_x(const float* __restrict__ x, char* __restrict__ xF) {
    const int i = blockIdx.x * blockDim.x + threadIdx.x;   // < 1048576
    const int lane = i & 63, ks = (i >> 6) & 15, rg = (i >> 10) & 3, t = i >> 12;
    const int m = lane & 15, quad = lane >> 4;
    const float* src = x + (size_t)(t * BB + rg * 16 + m) * IC + ks * 32 + quad * 8;
    f16 hi[8], lo[8];
#pragma unroll
    for (int j = 0; j < 8; ++j) split(src[j], hi[j], lo[j]);
    char* dst = xF + (size_t)i * 32;
    *(f16x8*)dst        = *(f16x8*)hi;
    *(f16x8*)(dst + 16) = *(f16x8*)lo;
}

__global__ void prep_wdf(const float* __restrict__ Wd, char* __restrict__ WDF) {
    const int i = blockIdx.x * blockDim.x + threadIdx.x;   // < 16384
    const int lane = i & 63, kd = (i >> 6) & 3, s = i >> 8;
    const int n = lane & 15, quad = lane >> 4;
    f16 hi[8], lo[8];
#pragma unroll
    for (int j = 0; j < 8; ++j) {
        const int k = kd * 32 + quad * 8 + j;
        const float v = (k < DC) ? Wd[(size_t)k * HC + 16 * s + n] : 0.0f;
        split(v, hi[j], lo[j]);
    }
    char* dst = WDF + (size_t)i * 32;
    *(f16x8*)dst        = *(f16x8*)hi;
    *(f16x8*)(dst + 16) = *(f16x8*)lo;
}

__global__ void prep_h0(const float* __restrict__ h0, char* __restrict__ hT,
                        unsigned* __restrict__ bar) {
    const int i = blockIdx.x * blockDim.x + threadIdx.x;   // < 8192
    const int lane = i & 63, ks = (i >> 6) & 31, rg = i >> 11;
    const int m = lane & 15, quad = lane >> 4;
    const float* src = h0 + (size_t)(rg * 16 + m) * HC + ks * 32 + quad * 8;
    f16 hi[8];
#pragma unroll
    for (int j = 0; j < 8; ++j) hi[j] = (f16)src[j];
    *(f16x8*)(hT + (size_t)i * 16) = *(f16x8*)hi;
    if (i < 2048) bar[i] = 0u;
}

__global__ void prep_d0(const float* __restrict__ d0, char* __restrict__ dT) {
    const int i = blockIdx.x * blockDim.x + threadIdx.x;   // < 1024
    const int lane = i & 63, kd = (i >> 6) & 3, rg = i >> 8;
    const int m = lane & 15, quad = lane >> 4;
    f16 hi[8], lo[8];
#pragma unroll
    for (int j = 0; j < 8; ++j) {
        const int k = kd * 32 + quad * 8 + j;
        const float v = (k < DC) ? d0[(size_t)(rg * 16 + m) * DC + k] : 0.0f;
        split(v, hi[j], lo[j]);
    }
    char* dst = dT + (size_t)i * 32;
    *(f16x8*)dst        = *(f16x8*)hi;
    *(f16x8*)(dst + 16) = *(f16x8*)lo;
}

// ------------------------------------------------------------- GEMM pieces

#define MFMA16(a, b, c) __builtin_amdgcn_mfma_f32_16x16x32_f16((a), (b), (c), 0, 0, 0)

// x-part: ks in [half*8, half*8+8), hi+lo loads, accs zero-inited.
__device__ __forceinline__ void xpart_gemm(
    const char* __restrict__ xb, const f16* __restrict__ BFH,
    const f16* __restrict__ BFL, const f16* __restrict__ RBF,
    int half, int lane, bool withr,
    f32x4& ghh, f32x4& ghl, f32x4& glh, f32x4& rh, f32x4& rl) {
    ghh = f32x4{0,0,0,0}; ghl = f32x4{0,0,0,0}; glh = f32x4{0,0,0,0};
    rh  = f32x4{0,0,0,0}; rl  = f32x4{0,0,0,0};
    const int k0 = half * 8;
#pragma unroll
    for (int i = 0; i < 8; ++i) {
        const int ks = k0 + i;
        const char* ap = xb + (size_t)(ks * 64 + lane) * 32;
        f16x8 ah = *(const f16x8*)ap;
        f16x8 al = *(const f16x8*)(ap + 16);
        f16x8 bh = *(const f16x8*)(BFH + (ks * 64 + lane) * 8);
        f16x8 bl = *(const f16x8*)(BFL + (ks * 64 + lane) * 8);
        ghh = MFMA16(ah, bh, ghh);
        ghl = MFMA16(ah, bl, ghl);
        glh = MFMA16(al, bh, glh);
        if (withr) {
            f16x8 rb = *(const f16x8*)(RBF + (ks * 64 + lane) * 8);
            if (i & 1) rl = MFMA16(ah, rb, rl);
            else       rh = MFMA16(ah, rb, rh);
        }
    }
}

// ------------------------------------------------------------- main kernel

template <bool TRAJ>
__global__ __launch_bounds__(NTHR) void sclstm_main(
    const char* __restrict__ xF, const char* __restrict__ WDF,
    char* hT, char* dT,
    const float* __restrict__ Wx, const float* __restrict__ Wh,
    const float* __restrict__ Wrx, const float* __restrict__ Wrh,
    const float* __restrict__ bvec, const float* __restrict__ c0,
    const float* __restrict__ d0, float* __restrict__ out,
    unsigned* bar) {

    const int g    = blockIdx.x;
    const int grp  = g & 7;
    const int tid  = threadIdx.x;
    const int w    = tid >> 6;
    const int half = w >> 2;                // K split
    const int wrow = w & 3;                 // 16-row A tile
    const int lane = tid & 63;
    const int n    = lane & 15;
    const int quad = lane >> 4;
    const bool withr = (g < NRB);

    // LDS map (155,904 B total)
    __shared__ __align__(16) char smem[155904];
    f16*  BFH = (f16*)(smem);                               // [48][64][8] gate B hi
    f16*  BFL = (f16*)(smem + 49152);                       // [48][64][8] gate B lo
    f16*  RBF = (f16*)(smem + 98304);                       // [48][64][8] r B hi
    float (*GL)[17]    = (float(*)[17])(smem + 147456);     // [64][17] gate preacts
    float (*TST)[16]   = (float(*)[16])(smem + 147456);     // stage (overlay GL)
    f32x4* PART        = (f32x4*)(smem + 151808);           // [4][64] split-K partials
    f16 (*DST)[32][16] = (f16(*)[32][16])(smem + 151808);   // [4][32][16] d stage (overlay)
    float (*DAL)[5]    = (float(*)[5])(smem + 151808);      // [64][5] (overlay)
    f16 (*HST)[16][4]  = (f16(*)[16][4])(smem + 151808 + 1280); // [4][16][4] h stage (hi)

    // ---------------- one-time: gate B-frags in LDS (2 ks rows per iter)
    for (int ks2 = 0; ks2 < 24; ++ks2) {
        if (tid < 128) {
            const int krow = tid >> 2, q = tid & 3;
            const int k = ks2 * 32 + krow;
            const float* W = (k < IC) ? (Wx + (size_t)k * NG)
                                      : (Wh + (size_t)(k - IC) * NG);
            const float4 v = *(const float4*)(W + q * HC + 4 * g);
            TST[krow][q * 4 + 0] = v.x; TST[krow][q * 4 + 1] = v.y;
            TST[krow][q * 4 + 2] = v.z; TST[krow][q * 4 + 3] = v.w;
        }
        __syncthreads();
        {
            const int e = tid;                  // 0..511
            const int le = e >> 3, j = e & 7;
            const float v = TST[(le >> 4) * 8 + j][le & 15];
            f16 hi, lo; split(v, hi, lo);
            const int ks = ks2 * 2;             // covers 32 k-rows = 1 ks... (2 passes)
            (void)ks;
        }
        // two frag rows (ks2*2? no: one TST pass = 32 k-rows = 1 ks). Write 1 ks:
#pragma unroll
        for (int e2 = 0; e2 < 1; ++e2) {
            const int e = tid;                  // 512 elems = 64 lanes * 8 j
            const int le = e >> 3, j = e & 7;
            const float v = TST[(le >> 4) * 8 + j][le & 15];
            f16 hi, lo; split(v, hi, lo);
            BFH[(ks2 * 64 + le) * 8 + j] = hi;
            BFL[(ks2 * 64 + le) * 8 + j] = lo;
        }
        __syncthreads();
    }
    // second half of ks rows (24..47)
    for (int ks2 = 24; ks2 < 48; ++ks2) {
        if (tid < 128) {
            const int krow = tid >> 2, q = tid & 3;
            const int k = ks2 * 32 + krow;
            const float* W = (k < IC) ? (Wx + (size_t)k * NG)
                                      : (Wh + (size_t)(k - IC) * NG);
            const float4 v = *(const float4*)(W + q * HC + 4 * g);
            TST[krow][q * 4 + 0] = v.x; TST[krow][q * 4 + 1] = v.y;
            TST[krow][q * 4 + 2] = v.z; TST[krow][q * 4 + 3] = v.w;
        }
        __syncthreads();
        {
            const int e = tid;
            const int le = e >> 3, j = e & 7;
            const float v = TST[(le >> 4) * 8 + j][le & 15];
            f16 hi, lo; split(v, hi, lo);
            BFH[(ks2 * 64 + le) * 8 + j] = hi;
            BFL[(ks2 * 64 + le) * 8 + j] = lo;
        }
        __syncthreads();
    }
    // one-time: r B-frags (hi only, alpha folded)
    if (withr) {
        for (int ks2 = 0; ks2 < 48; ++ks2) {
            if (tid < 128) {
                const int krow = tid >> 2, cg = tid & 3;
                const int k = ks2 * 32 + krow;
                const int col0 = 16 * g + cg * 4;
                float4 v = make_float4(0.f, 0.f, 0.f, 0.f);
                if (col0 < DC) {
                    if (k < IC) v = *(const float4*)(Wrx + (size_t)k * DC + col0);
                    else {
                        float4 u = *(const float4*)(Wrh + (size_t)(k - IC) * DC + col0);
                        v = make_float4(0.5f * u.x, 0.5f * u.y, 0.5f * u.z, 0.5f * u.w);
                    }
                }
                TST[krow][cg * 4 + 0] = v.x; TST[krow][cg * 4 + 1] = v.y;
                TST[krow][cg * 4 + 2] = v.z; TST[krow][cg * 4 + 3] = v.w;
            }
            __syncthreads();
            {
                const int e = tid;
                const int le = e >> 3, j = e & 7;
                RBF[(ks2 * 64 + le) * 8 + j] = (f16)TST[(le >> 4) * 8 + j][le & 15];
            }
            __syncthreads();
        }
    }

    // ---------------- per-thread state
    const float biasv = bvec[(n >> 2) * HC + g * 4 + (n & 3)];
    const int row2 = tid >> 2, jj = tid & 3;        // valid for tid < 256
    float c = 0.f;
    if (tid < 256) c = c0[(size_t)row2 * HC + 4 * g + jj];
    float d_prev[4] = {0.f, 0.f, 0.f, 0.f};
    if (withr && half == 0 && 16 * g + n < DC) {
#pragma unroll
        for (int r = 0; r < 4; ++r)
            d_prev[r] = d0[(size_t)(wrow * 16 + quad * 4 + r) * DC + 16 * g + n];
    }

    // Wd B-frags hoisted (step-invariant), held in 32 VGPRs by half0 waves
    f16x8 wph[4], wpl[4];
    if (half == 0) {
        const char* wb = WDF + (size_t)(g >> 2) * 8192;
#pragma unroll
        for (int kd = 0; kd < 4; ++kd) {
            const char* wp = wb + (size_t)(kd * 64 + lane) * 32;
            wph[kd] = *(const f16x8*)wp;
            wpl[kd] = *(const f16x8*)(wp + 16);
        }
    }
    __syncthreads();

    const int ksh = g >> 3, qkh = (g & 7) >> 1, jw = (g & 1) * 4;   // h-frag coords

    // prime accumulators with x-part of step 0
    f32x4 ghh, ghl, glh, rh, rl;
    xpart_gemm(xF + (size_t)wrow * 32768, BFH, BFL, RBF, half, lane, withr,
               ghh, ghl, glh, rh, rl);

    // ---------------- time loop
    for (int t = 0; t < TT; ++t) {
        const int slH  = TRAJ ? t : (t & 1);
        const int slH1 = TRAJ ? (t + 1) : ((t + 1) & 1);
        const int slD1 = slH1;
        const char* hb = hT + (size_t)slH * H_SLOT + (size_t)wrow * 32768;

        if (withr) {
            // ---- r-first: r h-loop, ah frags cached in registers ----
            f16x8 ahreg[16];
#pragma unroll
            for (int i = 0; i < 16; ++i) {
                const int ks = 16 + half * 16 + i;
                ahreg[i] = loadA16<TRAJ>(hb + (size_t)((ks - 16) * 64 + lane) * 16);
                f16x8 rb = *(const f16x8*)(RBF + (ks * 64 + lane) * 8);
                if (i & 1) rl = MFMA16(ahreg[i], rb, rl);
                else       rh = MFMA16(ahreg[i], rb, rh);
            }
            f32x4 accr = rh + rl;
            if (half == 1) PART[wrow * 64 + lane] = accr;
            __syncthreads();
            if (half == 0) {
                accr += PART[wrow * 64 + lane];
#pragma unroll
                for (int r = 0; r < 4; ++r) {
                    const float rv = fast_sigmoid(accr[r]);
                    const float dn = rv * d_prev[r];
                    d_prev[r] = dn;
                    f16 hi, lo; split(dn, hi, lo);
                    const int sr = (n >> 3) * 16 + quad * 4 + r;
                    DST[wrow][sr][n & 7]       = hi;
                    DST[wrow][sr][8 + (n & 7)] = lo;
                }
                if (t == TT - 1 && 16 * g + n < DC) {
#pragma unroll
                    for (int r = 0; r < 4; ++r)
                        out[OFF_D + (size_t)(wrow * 16 + quad * 4 + r) * DC + 16 * g + n] = d_prev[r];
                }
            }
            __syncthreads();
            if (tid < 256) {
                const int rg = tid >> 6, l32 = (tid >> 1) & 31, part = tid & 1;
                char* base = dT + (size_t)slD1 * D_SLOT;
                char* dp = base + (size_t)((rg * 4 + (g >> 1)) * 64 + 32 * (g & 1) + l32) * 32
                           + part * 8;
                astore8(dp,      *(const u64*)&DST[rg][l32][part * 4]);
                astore8(dp + 16, *(const u64*)&DST[rg][l32][8 + part * 4]);
                if (g == 6) {   // zero-fill d-frag cols 112..127
                    char* zp = base + (size_t)((rg * 4 + 3) * 64 + 32 + l32) * 32 + part * 8;
                    astore8(zp, 0ull); astore8(zp + 16, 0ull);
                }
            }
            __syncthreads();   // drain d stores (vmcnt 0) before relaxed signal
            if (tid == 0) {
                unsigned o = aadd4(bar + BAR_DCNT);
                if (o % NRB == NRB - 1) {
#pragma unroll
                    for (int e = 0; e < 8; ++e) astore4(bar + BAR_DEP(e), t + 1);
                }
            }
            // ---- gate h-loop from cached registers (no loads) ----
#pragma unroll
            for (int i = 0; i < 16; ++i) {
                const int ks = 16 + half * 16 + i;
                f16x8 bh = *(const f16x8*)(BFH + (ks * 64 + lane) * 8);
                f16x8 bl = *(const f16x8*)(BFL + (ks * 64 + lane) * 8);
                ghh = MFMA16(ahreg[i], bh, ghh);
                ghl = MFMA16(ahreg[i], bl, ghl);
            }
        } else {
            // ---- gate h-loop (hi-only loads, 2 MFMA streams) ----
#pragma unroll
            for (int i = 0; i < 16; ++i) {
                const int ks = 16 + half * 16 + i;
                f16x8 ah = loadA16<TRAJ>(hb + (size_t)((ks - 16) * 64 + lane) * 16);
                f16x8 bh = *(const f16x8*)(BFH + (ks * 64 + lane) * 8);
                f16x8 bl = *(const f16x8*)(BFL + (ks * 64 + lane) * 8);
                ghh = MFMA16(ah, bh, ghh);
                ghl = MFMA16(ah, bl, ghl);
            }
        }
        f32x4 accg = ghh + ghl + glh;

        // ---- split-K reduction (gate) + GL write ----
        if (half == 1) PART[wrow * 64 + lane] = accg;
        __syncthreads();                                   // S1
        if (half == 0) {
            accg += PART[wrow * 64 + lane];
#pragma unroll
            for (int r = 0; r < 4; ++r)
                GL[wrow * 16 + quad * 4 + r][n] = accg[r] + biasv;
        }
        __syncthreads();                                   // S2

        // ---- gate activations (before the d-wait) ----
        float iv = 0.f, fv = 0.f, gv = 0.f, ov = 0.f;
        if (tid < 256) {
            iv = fast_sigmoid(GL[row2][jj]);
            fv = fast_sigmoid(GL[row2][4 + jj]);
            gv = fast_tanh(GL[row2][8 + jj]);
            ov = fast_sigmoid(GL[row2][12 + jj]);
        }

        // ---- wait for d-ready broadcast (normally already set) ----
        if (tid == 0) {
            while (aload4(bar + BAR_DEP(grp)) < (unsigned)(t + 1))
                __builtin_amdgcn_s_sleep(1);
        }
        __syncthreads();                                   // S3

        // ---- da = d_new @ Wd (K=128, split precision, Wd in regs) ----
        if (half == 0) {
            f32x4 da = {0,0,0,0};
            const char* db = dT + (size_t)slD1 * D_SLOT + (size_t)wrow * 8192;
#pragma unroll
            for (int kd = 0; kd < 4; ++kd) {
                f16x8 dh, dl;
                loadAB<TRAJ>(db + (size_t)(kd * 64 + lane) * 32, dh, dl);
                da = MFMA16(dh, wph[kd], da);
                da = MFMA16(dh, wpl[kd], da);
                da = MFMA16(dl, wph[kd], da);
            }
            const int wo = n - 4 * (g & 3);
            if ((unsigned)wo < 4u) {
#pragma unroll
                for (int r = 0; r < 4; ++r)
                    DAL[wrow * 16 + quad * 4 + r][wo] = da[r];
            }
        }
        __syncthreads();                                   // S4

        // ---- c/h update (1 state/thread, threads 0..255) ----
        if (tid < 256) {
            c = fv * c + iv * gv + fast_tanh(DAL[row2][jj]);
            const float h = ov * fast_tanh(c);
            out[((size_t)t * BB + row2) * HC + 4 * g + jj] = h;
            HST[row2 >> 4][row2 & 15][jj] = (f16)h;
            if (t == TT - 1) {
                out[OFF_H + (size_t)row2 * HC + 4 * g + jj] = h;
                out[OFF_C + (size_t)row2 * HC + 4 * g + jj] = c;
            }
        }
        __syncthreads();                                   // S5

        // ---- publish h fragment (hi-only, 8B per row) ----
        if (tid < 64) {
            const int rg = tid >> 4, m = tid & 15;
            const u64 v = *(const u64*)&HST[rg][m][0];
            char* p = hT + (size_t)slH1 * H_SLOT + (size_t)rg * 32768
                      + (size_t)(ksh * 64 + qkh * 16 + m) * 16 + jw * 2;
            astore8(p, v);
        }
        __syncthreads();                                   // S6 (drain)

        // ---- split-phase hierarchical barrier ----
        if (tid == 0) {
            unsigned o = aadd4(bar + BAR_GRP(grp));
            if ((o & 31) == 31) {
                unsigned o2 = aadd4(bar + BAR_ROOT);
                if ((o2 & 7) == 7) {
#pragma unroll
                    for (int e = 0; e < 8; ++e) astore4(bar + BAR_EPOCH(e), t + 1);
                }
            }
        }

        // ---- overlap: x-part GEMM of step t+1 while epoch propagates ----
        if (t + 1 < TT) {
            xpart_gemm(xF + (size_t)((t + 1) * 4 + wrow) * 32768,
                       BFH, BFL, RBF, half, lane, withr, ghh, ghl, glh, rh, rl);
        }

        if (tid == 0) {
            while (aload4(bar + BAR_EPOCH(grp)) < (unsigned)(t + 1))
                __builtin_amdgcn_s_sleep(1);
        }
        __syncthreads();                                   // S7
    }
}

// ------------------------------------------------------------- launch

extern "C" void kernel_launch(void* const* d_in, const int* in_sizes, int n_in,
                              void* d_out, int out_size, void* d_ws, size_t ws_size,
                              hipStream_t stream) {
    const float* x   = (const float*)d_in[0];
    const float* h0  = (const float*)d_in[1];
    const float* c0  = (const float*)d_in[2];
    const float* d0  = (const float*)d_in[3];
    const float* Wx  = (const float*)d_in[4];
    const float* Wh  = (const float*)d_in[5];
    const float* bv  = (const float*)d_in[6];
    const float* Wrx = (const float*)d_in[7];
    const float* Wrh = (const float*)d_in[8];
    const float* Wd  = (const float*)d_in[9];
    float* out = (float*)d_out;

    char* ws = (char*)d_ws;
    const bool traj = (ws_size >= (size_t)WS_NEED_TRAJ);
    const int dslots = traj ? 257 : 2;

    unsigned* bar = (unsigned*)(ws + WS_BAR);
    char* xF  = ws + WS_X;
    char* WDF = ws + WS_WDF;
    char* dT  = ws + WS_D;
    char* hT  = dT + (size_t)dslots * D_SLOT;

    prep_x<<<4096, 256, 0, stream>>>(x, xF);
    prep_wdf<<<64, 256, 0, stream>>>(Wd, WDF);
    prep_h0<<<32, 256, 0, stream>>>(h0, hT, bar);
    prep_d0<<<4, 256, 0, stream>>>(d0, dT);

    if (traj)
        sclstm_main<true><<<NBLK, NTHR, 0, stream>>>(xF, WDF, hT, dT, Wx, Wh, Wrx, Wrh,
                                                     bv, c0, d0, out, bar);
    else
        sclstm_main<false><<<NBLK, NTHR, 0, stream>>>(xF, WDF, hT, dT, Wx, Wh, Wrx, Wrh,
                                                      bv, c0, d0, out, bar);
}